// Round 2
// baseline (2130.680 us; speedup 1.0000x reference)
//
#include <hip/hip_runtime.h>
#include <math.h>

// Problem constants (fixed by the reference)
#define NN 10000
#define EE 160000
#define FF 128
#define RR 20
#define LL 3
#define CUTOFF 3.0f
#define F3 384           // 3*F
#define PI_F 3.14159265358979323846f

// ---------------------------------------------------------------------------
// init: sfeat = emb[z], v = 0, dv = 0
__global__ __launch_bounds__(256) void k_init(const int* __restrict__ z,
                                              const float* __restrict__ emb,
                                              float* __restrict__ sfeat,
                                              float* __restrict__ v,
                                              float* __restrict__ dv) {
    int idx = blockIdx.x * 256 + threadIdx.x;
    if (idx < NN * 3 * FF) { v[idx] = 0.f; dv[idx] = 0.f; }
    if (idx < NN * FF) {
        int n = idx >> 7, f = idx & 127;
        sfeat[idx] = emb[z[n] * FF + f];
    }
}

// ---------------------------------------------------------------------------
// geometry per edge: dir[E,3], cut[E], rbf[E,R]
__global__ __launch_bounds__(256) void k_geom(const float* __restrict__ pos,
                                              const int* __restrict__ idx_i,
                                              const int* __restrict__ idx_j,
                                              float* __restrict__ dir,
                                              float* __restrict__ cutb,
                                              float* __restrict__ rbf) {
    int e = blockIdx.x * 256 + threadIdx.x;
    if (e >= EE) return;
    int i = idx_i[e], j = idx_j[e];
    float dx = pos[j * 3 + 0] - pos[i * 3 + 0];
    float dy = pos[j * 3 + 1] - pos[i * 3 + 1];
    float dz = pos[j * 3 + 2] - pos[i * 3 + 2];
    float sq = dx * dx + dy * dy + dz * dz;
    float dist = sq > 0.f ? sqrtf(sq) : 0.f;
    float inv = dist > 0.f ? 1.f / dist : 0.f;
    dir[e * 3 + 0] = dx * inv;
    dir[e * 3 + 1] = dy * inv;
    dir[e * 3 + 2] = dz * inv;
    cutb[e] = (dist < CUTOFF) ? 0.5f * (cosf(PI_F * dist / CUTOFF) + 1.f) : 0.f;
    float b = PI_F * dist / CUTOFF;
#pragma unroll
    for (int r = 0; r < RR; r++)
        rbf[e * RR + r] = sinf((float)(r + 1) * b) * inv;
}

// ---------------------------------------------------------------------------
// Generic fp32 MLP/GEMM: C[M,NOUT] = act(A_cat @ W + bias)
// A_cat rows are A[row, 0:KA] ++ A2[row, 0:KTOT-KA] (A2 null if KA==KTOT)
// block: 256 threads; ROWS rows per block (32 or 64 -> 1 or 2 rows/thread);
// 8 col-groups x 16 cols = 128-col tile. grid: (ceil(M/ROWS), NOUT/128)
// Static LDS kept <= 64KB: K=128/ROWS=64 -> 33KB; K=256/ROWS=32 -> 32.9KB.
template <int KTOT, int ROWS, bool SILU>
__global__ __launch_bounds__(256) void k_mlp(const float* __restrict__ A, int KA,
                                             const float* __restrict__ A2,
                                             const float* __restrict__ W,
                                             const float* __restrict__ bias,
                                             float* __restrict__ C, int M, int NOUT) {
    constexpr int RPT = ROWS / 32;   // rows per thread
    __shared__ float As[ROWS * (KTOT + 1)];
    const int tid = threadIdx.x;
    const int row0 = blockIdx.x * ROWS;
    const int K2 = KTOT - KA;
    for (int idx = tid; idx < ROWS * KTOT; idx += 256) {
        int r = idx / KTOT, k = idx - r * KTOT;
        int row = row0 + r;
        float val = 0.f;
        if (row < M) val = (k < KA) ? A[row * KA + k] : A2[row * K2 + (k - KA)];
        As[r * (KTOT + 1) + k] = val;
    }
    __syncthreads();
    const int r = tid >> 3;                       // 0..31
    const int c0 = blockIdx.y * 128 + (tid & 7) * 16;
    float acc[RPT][16];
#pragma unroll
    for (int p = 0; p < RPT; p++)
#pragma unroll
        for (int j = 0; j < 16; j++) acc[p][j] = bias ? bias[c0 + j] : 0.f;
    for (int k = 0; k < KTOT; k++) {
        const float4* w4 = reinterpret_cast<const float4*>(W + (size_t)k * NOUT + c0);
        float4 w0 = w4[0], w1 = w4[1], w2 = w4[2], w3 = w4[3];
#pragma unroll
        for (int p = 0; p < RPT; p++) {
            float a = As[(r + 32 * p) * (KTOT + 1) + k];
            acc[p][0]  += a * w0.x; acc[p][1]  += a * w0.y;
            acc[p][2]  += a * w0.z; acc[p][3]  += a * w0.w;
            acc[p][4]  += a * w1.x; acc[p][5]  += a * w1.y;
            acc[p][6]  += a * w1.z; acc[p][7]  += a * w1.w;
            acc[p][8]  += a * w2.x; acc[p][9]  += a * w2.y;
            acc[p][10] += a * w2.z; acc[p][11] += a * w2.w;
            acc[p][12] += a * w3.x; acc[p][13] += a * w3.y;
            acc[p][14] += a * w3.z; acc[p][15] += a * w3.w;
        }
    }
#pragma unroll
    for (int p = 0; p < RPT; p++) {
        int row = row0 + r + 32 * p;
        if (row < M) {
            float* crow = C + (size_t)row * NOUT + c0;
#pragma unroll
            for (int j = 0; j < 16; j++) {
                float x = acc[p][j];
                if (SILU) x = x / (1.f + expf(-x));
                crow[j] = x;
            }
        }
    }
}

// ---------------------------------------------------------------------------
// edge message: 512-thread block = 8 waves; 8 edges per wave; rbf_w/rbf_b in LDS.
//   W_c = cut * (rbf_b[c] + sum_r rbf[e,r]*rbf_w[r,c]);  phiW = phi[j,c]*W_c
//   split: cols 0:128 vv | 128:256 ss | 256:384 vs
//   sfeat[i] += ss (in place; phi precomputed so no read hazard)
//   dv[i,d,f] += v[j,d,f]*vv[f] + vs[f]*dir[d]
#define EPW 8
__global__ __launch_bounds__(512) void k_edge(const int* __restrict__ idx_i,
                                              const int* __restrict__ idx_j,
                                              const float* __restrict__ dir,
                                              const float* __restrict__ cutb,
                                              const float* __restrict__ rbf,
                                              const float* __restrict__ phi,
                                              const float* __restrict__ v,
                                              const float* __restrict__ rbf_w,
                                              const float* __restrict__ rbf_b,
                                              float* __restrict__ sfeat,
                                              float* __restrict__ dv) {
    __shared__ float sW[RR * F3 + F3];   // weights then bias: 8064 floats = 31.5KB
    for (int idx = threadIdx.x; idx < RR * F3; idx += 512) sW[idx] = rbf_w[idx];
    for (int idx = threadIdx.x; idx < F3; idx += 512) sW[RR * F3 + idx] = rbf_b[idx];
    __syncthreads();
    const int wave = threadIdx.x >> 6, lane = threadIdx.x & 63;
    const int e0 = blockIdx.x * (8 * EPW) + wave * EPW;
    for (int ee = 0; ee < EPW; ee++) {
        const int e = e0 + ee;
        const float c = cutb[e];
        if (c == 0.f) continue;             // wave-uniform: beyond-cutoff edge = 0
        const int i = idx_i[e], j = idx_j[e];
        const float d0 = dir[e * 3 + 0], d1 = dir[e * 3 + 1], d2 = dir[e * 3 + 2];
        float rb[RR];
#pragma unroll
        for (int rr = 0; rr < RR; rr++) rb[rr] = rbf[e * RR + rr];  // broadcast loads
        float pw[6];
#pragma unroll
        for (int cb = 0; cb < 6; cb++) {
            const int col = cb * 64 + lane;
            float w = sW[RR * F3 + col];
#pragma unroll
            for (int rr = 0; rr < RR; rr++) w += rb[rr] * sW[rr * F3 + col];
            pw[cb] = phi[(size_t)j * F3 + col] * (w * c);
        }
        // scalar-feature scatter (cols 128..255 => f = lane, lane+64)
        atomicAdd(&sfeat[i * FF + lane], pw[2]);
        atomicAdd(&sfeat[i * FF + 64 + lane], pw[3]);
        // vector-feature scatter into delta buffer
#pragma unroll
        for (int d = 0; d < 3; d++) {
            const float dd = (d == 0) ? d0 : ((d == 1) ? d1 : d2);
            const float vj0 = v[(size_t)j * F3 + d * FF + lane];
            const float vj1 = v[(size_t)j * F3 + d * FF + 64 + lane];
            atomicAdd(&dv[(size_t)i * F3 + d * FF + lane],      vj0 * pw[0] + pw[4] * dd);
            atomicAdd(&dv[(size_t)i * F3 + d * FF + 64 + lane], vj1 * pw[1] + pw[5] * dd);
        }
    }
}

// ---------------------------------------------------------------------------
// v += dv; dv = 0
__global__ __launch_bounds__(256) void k_applydv(float* __restrict__ v,
                                                 float* __restrict__ dv) {
    int idx = blockIdx.x * 256 + threadIdx.x;
    if (idx < NN * 3 * FF) { v[idx] += dv[idx]; dv[idx] = 0.f; }
}

// ---------------------------------------------------------------------------
// per (n,g): vnorm = safe_norm(Vv[n,g,:]), dot = <Uv[n,g,:],Vv[n,g,:]>
__global__ __launch_bounds__(256) void k_normdot(const float* __restrict__ Uv,
                                                 const float* __restrict__ Vv,
                                                 float* __restrict__ vnorm,
                                                 float* __restrict__ dotb) {
    int idx = blockIdx.x * 256 + threadIdx.x;
    if (idx >= NN * FF) return;
    int n = idx >> 7, g = idx & 127;
    const float* uv = Uv + (size_t)n * F3 + g;
    const float* vv = Vv + (size_t)n * F3 + g;
    float u0 = uv[0], u1 = uv[FF], u2 = uv[2 * FF];
    float w0 = vv[0], w1 = vv[FF], w2 = vv[2 * FF];
    float sq = w0 * w0 + w1 * w1 + w2 * w2;
    vnorm[idx] = sq > 0.f ? sqrtf(sq) : 0.f;
    dotb[idx] = u0 * w0 + u1 * w1 + u2 * w2;
}

// ---------------------------------------------------------------------------
// gated update: v[n,:,g] += Uv[n,:,g]*a_vv;  s[n,g] += a_ss + a_sv*dot
// a layout [N,384] = [a_vv | a_sv | a_ss]
__global__ __launch_bounds__(256) void k_update(const float* __restrict__ a,
                                                const float* __restrict__ Uv,
                                                const float* __restrict__ dotb,
                                                float* __restrict__ v,
                                                float* __restrict__ sfeat) {
    int idx = blockIdx.x * 256 + threadIdx.x;
    if (idx >= NN * FF) return;
    int n = idx >> 7, g = idx & 127;
    float avv = a[(size_t)n * F3 + g];
    float asv = a[(size_t)n * F3 + 128 + g];
    float ass = a[(size_t)n * F3 + 256 + g];
#pragma unroll
    for (int d = 0; d < 3; d++)
        v[(size_t)n * F3 + d * FF + g] += Uv[(size_t)n * F3 + d * FF + g] * avv;
    sfeat[idx] += ass + asv * dotb[idx];
}

// ---------------------------------------------------------------------------
// transpose internal v[N,3,F] -> output vfeat[N,F,3]
__global__ __launch_bounds__(256) void k_outv(const float* __restrict__ v,
                                              float* __restrict__ outv) {
    int idx = blockIdx.x * 256 + threadIdx.x;
    if (idx >= NN * FF * 3) return;
    int n = idx / F3;
    int rem = idx - n * F3;
    int f = rem / 3;
    int d = rem - f * 3;
    outv[idx] = v[n * F3 + d * FF + f];
}

// ---------------------------------------------------------------------------
extern "C" void kernel_launch(void* const* d_in, const int* in_sizes, int n_in,
                              void* d_out, int out_size, void* d_ws, size_t ws_size,
                              hipStream_t stream) {
    const int*   z      = (const int*)d_in[0];
    const float* pos    = (const float*)d_in[1];
    const int*   idx_i  = (const int*)d_in[2];
    const int*   idx_j  = (const int*)d_in[3];
    const float* emb    = (const float*)d_in[4];
    const float* msg_w1 = (const float*)d_in[5];
    const float* msg_b1 = (const float*)d_in[6];
    const float* msg_w2 = (const float*)d_in[7];
    const float* msg_b2 = (const float*)d_in[8];
    const float* rbf_w  = (const float*)d_in[9];
    const float* rbf_b  = (const float*)d_in[10];
    const float* upd_U  = (const float*)d_in[11];
    const float* upd_V  = (const float*)d_in[12];
    const float* upd_w1 = (const float*)d_in[13];
    const float* upd_b1 = (const float*)d_in[14];
    const float* upd_w2 = (const float*)d_in[15];
    const float* upd_b2 = (const float*)d_in[16];

    float* sfeat = (float*)d_out;            // [N,F]
    float* outv  = sfeat + NN * FF;          // [N,F,3]

    float* ws    = (float*)d_ws;
    float* v     = ws;                       // [N,3,F]
    float* dv    = v + NN * F3;              // [N,3,F]
    float* phi   = dv + NN * F3;             // [N,3F] (also 'a')
    float* h     = phi + NN * F3;            // [N,F]
    float* Uv    = h + NN * FF;              // [N,3,F]
    float* Vv    = Uv + NN * F3;             // [N,3,F]
    float* vnorm = Vv + NN * F3;             // [N,F]
    float* dotb  = vnorm + NN * FF;          // [N,F]
    float* rbf   = dotb + NN * FF;           // [E,R]
    float* cutb  = rbf + EE * RR;            // [E]
    float* dirb  = cutb + EE;                // [E,3]

    const dim3 blk(256);
    const dim3 g_nf3((NN * 3 * FF) / 256);   // 15000
    const dim3 g_nf((NN * FF) / 256);        // 5000
    const dim3 g_e((EE + 255) / 256);        // 625
    const dim3 g_edge(EE / 64);              // 2500 (8 waves/block, 8 edges/wave)

    k_init<<<g_nf3, blk, 0, stream>>>(z, emb, sfeat, v, dv);
    k_geom<<<g_e, blk, 0, stream>>>(pos, idx_i, idx_j, dirb, cutb, rbf);

    const int gM_N64  = (NN + 63) / 64;      // 157
    const int gM_N32  = (NN + 31) / 32;      // 313
    const int gM_3N64 = (3 * NN + 63) / 64;  // 469

    for (int l = 0; l < LL; l++) {
        const float* mw1 = msg_w1 + l * FF * FF;
        const float* mb1 = msg_b1 + l * FF;
        const float* mw2 = msg_w2 + l * FF * F3;
        const float* mb2 = msg_b2 + l * F3;
        const float* rw  = rbf_w + l * RR * F3;
        const float* rb  = rbf_b + l * F3;
        const float* uU  = upd_U + l * FF * FF;
        const float* uV  = upd_V + l * FF * FF;
        const float* uw1 = upd_w1 + l * 2 * FF * FF;
        const float* ub1 = upd_b1 + l * FF;
        const float* uw2 = upd_w2 + l * FF * F3;
        const float* ub2 = upd_b2 + l * F3;

        // message MLP: h = silu(s@w1+b1); phi = h@w2+b2
        k_mlp<128, 64, true><<<dim3(gM_N64, 1), blk, 0, stream>>>(sfeat, 128, nullptr, mw1, mb1, h, NN, 128);
        k_mlp<128, 64, false><<<dim3(gM_N64, 3), blk, 0, stream>>>(h, 128, nullptr, mw2, mb2, phi, NN, F3);

        // edge scatter (reads pre-layer v, accumulates into dv; sfeat in place)
        k_edge<<<g_edge, dim3(512), 0, stream>>>(idx_i, idx_j, dirb, cutb, rbf, phi, v, rw, rb, sfeat, dv);

        // v += dv; dv = 0
        k_applydv<<<g_nf3, blk, 0, stream>>>(v, dv);

        // Uv/Vv: [3N,128] @ [128,128]
        k_mlp<128, 64, false><<<dim3(gM_3N64, 1), blk, 0, stream>>>(v, 128, nullptr, uU, nullptr, Uv, 3 * NN, 128);
        k_mlp<128, 64, false><<<dim3(gM_3N64, 1), blk, 0, stream>>>(v, 128, nullptr, uV, nullptr, Vv, 3 * NN, 128);

        k_normdot<<<g_nf, blk, 0, stream>>>(Uv, Vv, vnorm, dotb);

        // update MLP: x = [vnorm | sfeat]; h = silu(x@w1+b1); a = h@w2+b2
        k_mlp<256, 32, true><<<dim3(gM_N32, 1), blk, 0, stream>>>(vnorm, 128, sfeat, uw1, ub1, h, NN, 128);
        k_mlp<128, 64, false><<<dim3(gM_N64, 3), blk, 0, stream>>>(h, 128, nullptr, uw2, ub2, phi, NN, F3);

        k_update<<<g_nf, blk, 0, stream>>>(phi, Uv, dotb, v, sfeat);
    }

    k_outv<<<(NN * FF * 3 + 255) / 256, blk, 0, stream>>>(v, outv);
}